// Round 1
// baseline (682.964 us; speedup 1.0000x reference)
//
#include <hip/hip_runtime.h>
#include <hip/hip_bf16.h>

// KAN 2-layer forward, MI355X (gfx950).
// Layer = GEMM over augmented features: k = channel*8 + j,
//   j=0: silu(x), j=1..6: cubic B-spline basis, j=7: zero pad.
// Weights folded as Waug[o][i*8+j] = {base_w[o][i], spline_w[o][i][j-1]*scaler[o][i], 0} in bf16.

typedef __attribute__((ext_vector_type(8))) short bf16x8;   // 8 x bf16 (4 VGPRs)
typedef __attribute__((ext_vector_type(4))) float f32x4;

#define TOKENS 8192
#define D_IN   256
#define D_HID  1024

// ---------------- feature function (matches reference Cox-de Boor, fp32) ----------------
__device__ __forceinline__ void kan_features(float x, float f[8]) {
    // silu
    f[0] = x / (1.0f + __expf(-x));
    // order-0: knots t_j = (j-3)*(2/3) - 1, j = 0..9
    const float h = 2.0f / 3.0f;
    float b[9];
#pragma unroll
    for (int m = 0; m < 9; ++m) {
        float t0 = (m - 3) * h - 1.0f;
        float t1 = (m - 2) * h - 1.0f;
        b[m] = (x >= t0 && x < t1) ? 1.0f : 0.0f;
    }
#pragma unroll
    for (int k = 1; k <= 3; ++k) {
#pragma unroll
        for (int m = 0; m < 9 - k; ++m) {
            float tm   = (m - 3) * h - 1.0f;
            float tmk  = (m - 3 + k) * h - 1.0f;
            float tm1  = (m - 2) * h - 1.0f;
            float tmk1 = (m - 2 + k) * h - 1.0f;
            b[m] = (x - tm) / (tmk - tm) * b[m] + (tmk1 - x) / (tmk1 - tm1) * b[m + 1];
        }
    }
#pragma unroll
    for (int j = 0; j < 6; ++j) f[1 + j] = b[j];
    f[7] = 0.0f;
}

// ---------------- weight prep: fold scaler, pad 7->8, cast bf16 ----------------
__global__ void prep_weights(const float* __restrict__ bw,
                             const float* __restrict__ sw,
                             const float* __restrict__ sc,
                             __hip_bfloat16* __restrict__ Waug,
                             int total /* OUT*IN */) {
    int idx = blockIdx.x * blockDim.x + threadIdx.x;
    if (idx >= total) return;
    float base = bw[idx];
    float scl  = sc[idx];
    __hip_bfloat16 row[8];
    row[0] = __float2bfloat16(base);
#pragma unroll
    for (int j = 0; j < 6; ++j)
        row[1 + j] = __float2bfloat16(sw[idx * 6 + j] * scl);
    row[7] = __float2bfloat16(0.0f);
    *(bf16x8*)&Waug[(size_t)idx * 8] = *(bf16x8*)row;
}

// ---------------- LDS swizzle: rows of 64 bf16 (128B), slot XOR (row&7) ----------------
// 16B-aligned always; spreads the 16 frag-read rows across 8 bank groups (2-way, free).
__device__ __forceinline__ int swz(int row, int slot) {
    return row * 128 + (((slot & 7) * 16) ^ ((row & 7) * 16));
}

// ---------------- fused KAN GEMM ----------------
// X: (N, IN) fp32.  W: (OUT, IN*8) bf16.  Y: (N, OUT) fp32 (optionally exact-GELU'd).
template<int BM, int BN, int WGM, int WGN, bool GELU_OUT>
__global__ __launch_bounds__(WGM * WGN * 64)
void kan_gemm(const float* __restrict__ X, const __hip_bfloat16* __restrict__ W,
              float* __restrict__ Y, int IN, int OUT) {
    constexpr int NTHR = WGM * WGN * 64;
    constexpr int WTM = BM / WGM, WTN = BN / WGN;
    constexpr int FM = WTM / 16, FN = WTN / 16;
    const int K = IN * 8;

    __shared__ char Alds[BM * 128];
    __shared__ char Blds[BN * 128];

    const int tid = threadIdx.x;
    const int wid = tid >> 6, lane = tid & 63;
    const int wm = wid / WGN, wn = wid % WGN;
    const int lr = lane & 15, lg = lane >> 4;

    const int n0 = blockIdx.x * BM;
    const int o0 = blockIdx.y * BN;

    f32x4 acc[FM][FN] = {};

    const int nchunk = IN / 4;           // 4 channels (=32 k) per chunk
    for (int kc = 0; kc < nchunk; ++kc) {
        const int i0 = kc * 4;
        if (kc) __syncthreads();
        // ---- stage A: compute features for 4 channels x BM rows ----
#pragma unroll
        for (int p = 0; p < (BM * 4) / NTHR; ++p) {
            int item = tid + p * NTHR;
            int n = item >> 2, io = item & 3;
            float xv = X[(size_t)(n0 + n) * IN + i0 + io];
            float f[8];
            kan_features(xv, f);
            __hip_bfloat16 fb[8];
#pragma unroll
            for (int j = 0; j < 8; ++j) fb[j] = __float2bfloat16(f[j]);
            *(bf16x8*)(Alds + swz(n, io)) = *(bf16x8*)fb;
        }
        // ---- stage B: weight tile ----
#pragma unroll
        for (int p = 0; p < (BN * 4) / NTHR; ++p) {
            int item = tid + p * NTHR;
            int o = item >> 2, seg = item & 3;
            bf16x8 wv = *(const bf16x8*)&W[(size_t)(o0 + o) * K + kc * 32 + seg * 8];
            *(bf16x8*)(Blds + swz(o, seg)) = wv;
        }
        __syncthreads();
        // ---- fragments + MFMA ----
        bf16x8 af[FM], bfr[FN];
#pragma unroll
        for (int fm = 0; fm < FM; ++fm)
            af[fm] = *(const bf16x8*)(Alds + swz(wm * WTM + fm * 16 + lr, lg));
#pragma unroll
        for (int fn = 0; fn < FN; ++fn)
            bfr[fn] = *(const bf16x8*)(Blds + swz(wn * WTN + fn * 16 + lr, lg));
#pragma unroll
        for (int fm = 0; fm < FM; ++fm)
#pragma unroll
            for (int fn = 0; fn < FN; ++fn)
                acc[fm][fn] = __builtin_amdgcn_mfma_f32_16x16x32_bf16(
                    af[fm], bfr[fn], acc[fm][fn], 0, 0, 0);
    }
    // ---- epilogue: C/D layout col=lane&15, row=(lane>>4)*4+r ----
#pragma unroll
    for (int fm = 0; fm < FM; ++fm) {
        int row = n0 + wm * WTM + fm * 16 + lg * 4;
#pragma unroll
        for (int fn = 0; fn < FN; ++fn) {
            int col = o0 + wn * WTN + fn * 16 + lr;
#pragma unroll
            for (int r = 0; r < 4; ++r) {
                float v = acc[fm][fn][r];
                if (GELU_OUT) v = 0.5f * v * (1.0f + erff(v * 0.70710678118f));
                Y[(size_t)(row + r) * OUT + col] = v;
            }
        }
    }
}

extern "C" void kernel_launch(void* const* d_in, const int* in_sizes, int n_in,
                              void* d_out, int out_size, void* d_ws, size_t ws_size,
                              hipStream_t stream) {
    const float* x   = (const float*)d_in[0];
    const float* bw1 = (const float*)d_in[1];
    const float* sw1 = (const float*)d_in[2];
    const float* sc1 = (const float*)d_in[3];
    const float* bw2 = (const float*)d_in[4];
    const float* sw2 = (const float*)d_in[5];
    const float* sc2 = (const float*)d_in[6];
    float* out = (float*)d_out;

    char* ws = (char*)d_ws;
    __hip_bfloat16* W1 = (__hip_bfloat16*)ws;                          // 1024*2048 bf16 = 4MB
    __hip_bfloat16* W2 = (__hip_bfloat16*)(ws + (4u << 20));           // 256*8192  bf16 = 4MB
    float* hbuf        = (float*)(ws + (8u << 20));                    // 8192*1024 f32 = 32MB

    size_t need = (8ull << 20) + (size_t)TOKENS * D_HID * sizeof(float);
    if (ws_size < need) return;  // fail loudly (validation will catch)

    const int totW = D_HID * D_IN;  // 262144, same both layers
    prep_weights<<<(totW + 255) / 256, 256, 0, stream>>>(bw1, sw1, sc1, W1, totW);
    prep_weights<<<(totW + 255) / 256, 256, 0, stream>>>(bw2, sw2, sc2, W2, totW);

    // Layer 1: (8192 x 2048aug) @ (2048aug x 1024) + GELU -> hbuf
    kan_gemm<128, 128, 2, 2, true>
        <<<dim3(TOKENS / 128, D_HID / 128), 256, 0, stream>>>(x, W1, hbuf, D_IN, D_HID);
    // Layer 2: (8192 x 8192aug) @ (8192aug x 256) -> out
    kan_gemm<64, 128, 2, 2, false>
        <<<dim3(TOKENS / 64, D_IN / 128), 256, 0, stream>>>(hbuf, W2, out, D_HID, D_IN);
}

// Round 2
// 204.887 us; speedup vs baseline: 3.3334x; 3.3334x over previous
//
#include <hip/hip_runtime.h>
#include <hip/hip_bf16.h>

// KAN 2-layer forward, MI355X (gfx950) — round 2.
// Pipeline (tier A, ws >= 168MB):
//   prep_weights x2 : fold scaler into spline w, pad 7->8, bf16  (W1 4MB, W2 4MB)
//   expand_x        : x -> F1 features (8192 x 256*8) bf16        (32MB)
//   kan_gemm_f<EPI=1>: F1 @ W1^T, epilogue = exact GELU + feature-expand -> F2 (128MB)
//   kan_gemm_f<EPI=2>: F2 @ W2^T, split-K=2, atomicAdd into zeroed d_out
// Tier C fallback (ws < 168MB): round-1 fused kernel (needs 40MB, proven).

typedef __attribute__((ext_vector_type(8))) short bf16x8;   // 8 x bf16 (4 VGPRs)
typedef __attribute__((ext_vector_type(4))) float f32x4;

#define TOKENS 8192
#define D_IN   256
#define D_HID  1024

// ---------------- feature function (Cox-de Boor, uniform knots => reciprocal mults) ----
__device__ __forceinline__ void kan_features(float x, float f[8]) {
    f[0] = x / (1.0f + __expf(-x));             // silu
    const float h = 2.0f / 3.0f;
    float b[9];
#pragma unroll
    for (int m = 0; m < 9; ++m) {
        float t0 = (m - 3) * h - 1.0f;
        float t1 = (m - 2) * h - 1.0f;
        b[m] = (x >= t0 && x < t1) ? 1.0f : 0.0f;
    }
#pragma unroll
    for (int k = 1; k <= 3; ++k) {
        const float inv = 1.0f / (k * h);       // compile-time constant (uniform grid)
#pragma unroll
        for (int m = 0; m < 9 - k; ++m) {
            float tm   = (m - 3) * h - 1.0f;
            float tmk1 = (m - 2 + k) * h - 1.0f;
            b[m] = (x - tm) * inv * b[m] + (tmk1 - x) * inv * b[m + 1];
        }
    }
#pragma unroll
    for (int j = 0; j < 6; ++j) f[1 + j] = b[j];
    f[7] = 0.0f;
}

__device__ __forceinline__ void features_to_bf16(const float f[8], __hip_bfloat16 fb[8]) {
#pragma unroll
    for (int j = 0; j < 8; ++j) fb[j] = __float2bfloat16(f[j]);
}

// ---------------- weight prep ----------------
__global__ void prep_weights(const float* __restrict__ bw,
                             const float* __restrict__ sw,
                             const float* __restrict__ sc,
                             __hip_bfloat16* __restrict__ Waug,
                             int total /* OUT*IN */) {
    int idx = blockIdx.x * blockDim.x + threadIdx.x;
    if (idx >= total) return;
    float scl = sc[idx];
    __hip_bfloat16 row[8];
    row[0] = __float2bfloat16(bw[idx]);
#pragma unroll
    for (int j = 0; j < 6; ++j)
        row[1 + j] = __float2bfloat16(sw[idx * 6 + j] * scl);
    row[7] = __float2bfloat16(0.0f);
    *(bf16x8*)&Waug[(size_t)idx * 8] = *(bf16x8*)row;
}

// ---------------- x -> features, once ----------------
__global__ void expand_x(const float* __restrict__ X, __hip_bfloat16* __restrict__ F,
                         int total) {
    int idx = blockIdx.x * blockDim.x + threadIdx.x;
    if (idx >= total) return;
    float f[8];
    kan_features(X[idx], f);
    __hip_bfloat16 fb[8];
    features_to_bf16(f, fb);
    *(bf16x8*)&F[(size_t)idx * 8] = *(bf16x8*)fb;
}

// ---------------- m97-structure GEMM: C = A(M,K) @ W(OUT,K)^T ----------------
// EPI: 0 = plain f32 store, 1 = exact-GELU + feature-expand -> Fout (bf16x8/elem),
//      2 = atomicAdd f32 (split-K over blockIdx.z)
template<int BM, int BN, int EPI>
__global__ __launch_bounds__(256)
void kan_gemm_f(const __hip_bfloat16* __restrict__ A,
                const __hip_bfloat16* __restrict__ W,
                float* __restrict__ Y,
                __hip_bfloat16* __restrict__ Fout,
                int K, int OUT) {
    constexpr int WTM = BM / 2, WTN = BN / 2;
    constexpr int FM = WTM / 16, FN = WTN / 16;
    __shared__ __hip_bfloat16 Al[BM * 32];
    __shared__ __hip_bfloat16 Bl[BN * 32];

    const int tid = threadIdx.x;
    const int wid = tid >> 6, lane = tid & 63;
    const int wm = wid >> 1, wn = wid & 1;
    const int lr = lane & 15, lg = lane >> 4;
    const int n0 = blockIdx.x * BM;
    const int o0 = blockIdx.y * BN;

    const int nsteps = K / 32;
    const int per = nsteps / gridDim.z;
    const int ks0 = blockIdx.z * per, ks1 = ks0 + per;

    f32x4 acc[FM][FN] = {};

    for (int kc = ks0; kc < ks1; ++kc) {
        // ---- stage A tile: BM rows x 32 bf16 (64B/row), global_load_lds width 16 ----
        constexpr int AI = BM * 64 / 4096;
#pragma unroll
        for (int p = 0; p < AI; ++p) {
            int item = tid + p * 256;
            int row = item >> 2, seg = item & 3;
            const __hip_bfloat16* src = A + (size_t)(n0 + row) * K + kc * 32 + seg * 8;
            __builtin_amdgcn_global_load_lds(
                (const __attribute__((address_space(1))) void*)src,
                (__attribute__((address_space(3))) void*)&Al[item * 8], 16, 0, 0);
        }
        constexpr int BI = BN * 64 / 4096;
#pragma unroll
        for (int p = 0; p < BI; ++p) {
            int item = tid + p * 256;
            int row = item >> 2, seg = item & 3;
            const __hip_bfloat16* src = W + (size_t)(o0 + row) * K + kc * 32 + seg * 8;
            __builtin_amdgcn_global_load_lds(
                (const __attribute__((address_space(1))) void*)src,
                (__attribute__((address_space(3))) void*)&Bl[item * 8], 16, 0, 0);
        }
        __syncthreads();
        // ---- fragments + MFMA ----
        bf16x8 af[FM], bfr[FN];
#pragma unroll
        for (int fm = 0; fm < FM; ++fm)
            af[fm] = *(const bf16x8*)&Al[(wm * WTM + fm * 16 + lr) * 32 + lg * 8];
#pragma unroll
        for (int fn = 0; fn < FN; ++fn)
            bfr[fn] = *(const bf16x8*)&Bl[(wn * WTN + fn * 16 + lr) * 32 + lg * 8];
#pragma unroll
        for (int fm = 0; fm < FM; ++fm)
#pragma unroll
            for (int fn = 0; fn < FN; ++fn)
                acc[fm][fn] = __builtin_amdgcn_mfma_f32_16x16x32_bf16(
                    af[fm], bfr[fn], acc[fm][fn], 0, 0, 0);
        __syncthreads();
    }

    // ---- epilogue: C/D layout col=lane&15, row=(lane>>4)*4+r ----
#pragma unroll
    for (int fm = 0; fm < FM; ++fm) {
#pragma unroll
        for (int fn = 0; fn < FN; ++fn) {
            int col = o0 + wn * WTN + fn * 16 + lr;
#pragma unroll
            for (int r = 0; r < 4; ++r) {
                int row = n0 + wm * WTM + fm * 16 + lg * 4 + r;
                float v = acc[fm][fn][r];
                if (EPI == 0) {
                    Y[(size_t)row * OUT + col] = v;
                } else if (EPI == 1) {
                    float g = 0.5f * v * (1.0f + erff(v * 0.70710678118f));
                    float f[8];
                    kan_features(g, f);
                    __hip_bfloat16 fb[8];
                    features_to_bf16(f, fb);
                    *(bf16x8*)&Fout[((size_t)row * OUT + col) * 8] = *(bf16x8*)fb;
                } else {
                    atomicAdd(&Y[(size_t)row * OUT + col], v);
                }
            }
        }
    }
}

// ================= Tier C fallback: round-1 fused kernel (needs 40MB ws) ==========
__device__ __forceinline__ int swz(int row, int slot) {
    return row * 128 + (((slot & 7) * 16) ^ ((row & 7) * 16));
}

template<int BM, int BN, int WGM, int WGN, bool GELU_OUT>
__global__ __launch_bounds__(WGM * WGN * 64)
void kan_gemm_fused(const float* __restrict__ X, const __hip_bfloat16* __restrict__ W,
                    float* __restrict__ Y, int IN, int OUT) {
    constexpr int NTHR = WGM * WGN * 64;
    constexpr int WTM = BM / WGM, WTN = BN / WGN;
    constexpr int FM = WTM / 16, FN = WTN / 16;
    const int K = IN * 8;

    __shared__ char Alds[BM * 128];
    __shared__ char Blds[BN * 128];

    const int tid = threadIdx.x;
    const int wid = tid >> 6, lane = tid & 63;
    const int wm = wid / WGN, wn = wid % WGN;
    const int lr = lane & 15, lg = lane >> 4;
    const int n0 = blockIdx.x * BM;
    const int o0 = blockIdx.y * BN;

    f32x4 acc[FM][FN] = {};

    const int nchunk = IN / 4;
    for (int kc = 0; kc < nchunk; ++kc) {
        const int i0 = kc * 4;
        if (kc) __syncthreads();
#pragma unroll
        for (int p = 0; p < (BM * 4) / NTHR; ++p) {
            int item = tid + p * NTHR;
            int n = item >> 2, io = item & 3;
            float xv = X[(size_t)(n0 + n) * IN + i0 + io];
            float f[8];
            kan_features(xv, f);
            __hip_bfloat16 fb[8];
            features_to_bf16(f, fb);
            *(bf16x8*)(Alds + swz(n, io)) = *(bf16x8*)fb;
        }
#pragma unroll
        for (int p = 0; p < (BN * 4) / NTHR; ++p) {
            int item = tid + p * NTHR;
            int o = item >> 2, seg = item & 3;
            bf16x8 wv = *(const bf16x8*)&W[(size_t)(o0 + o) * K + kc * 32 + seg * 8];
            *(bf16x8*)(Blds + swz(o, seg)) = wv;
        }
        __syncthreads();
        bf16x8 af[FM], bfr[FN];
#pragma unroll
        for (int fm = 0; fm < FM; ++fm)
            af[fm] = *(const bf16x8*)(Alds + swz(wm * WTM + fm * 16 + lr, lg));
#pragma unroll
        for (int fn = 0; fn < FN; ++fn)
            bfr[fn] = *(const bf16x8*)(Blds + swz(wn * WTN + fn * 16 + lr, lg));
#pragma unroll
        for (int fm = 0; fm < FM; ++fm)
#pragma unroll
            for (int fn = 0; fn < FN; ++fn)
                acc[fm][fn] = __builtin_amdgcn_mfma_f32_16x16x32_bf16(
                    af[fm], bfr[fn], acc[fm][fn], 0, 0, 0);
    }
#pragma unroll
    for (int fm = 0; fm < FM; ++fm) {
        int row = n0 + wm * WTM + fm * 16 + lg * 4;
#pragma unroll
        for (int fn = 0; fn < FN; ++fn) {
            int col = o0 + wn * WTN + fn * 16 + lr;
#pragma unroll
            for (int r = 0; r < 4; ++r) {
                float v = acc[fm][fn][r];
                if (GELU_OUT) v = 0.5f * v * (1.0f + erff(v * 0.70710678118f));
                Y[(size_t)(row + r) * OUT + col] = v;
            }
        }
    }
}

extern "C" void kernel_launch(void* const* d_in, const int* in_sizes, int n_in,
                              void* d_out, int out_size, void* d_ws, size_t ws_size,
                              hipStream_t stream) {
    const float* x   = (const float*)d_in[0];
    const float* bw1 = (const float*)d_in[1];
    const float* sw1 = (const float*)d_in[2];
    const float* sc1 = (const float*)d_in[3];
    const float* bw2 = (const float*)d_in[4];
    const float* sw2 = (const float*)d_in[5];
    const float* sc2 = (const float*)d_in[6];
    float* out = (float*)d_out;

    char* ws = (char*)d_ws;
    __hip_bfloat16* W1 = (__hip_bfloat16*)ws;                  // 4MB
    __hip_bfloat16* W2 = (__hip_bfloat16*)(ws + (4ull << 20)); // 4MB

    const int totW = D_HID * D_IN;
    prep_weights<<<(totW + 255) / 256, 256, 0, stream>>>(bw1, sw1, sc1, W1, totW);
    prep_weights<<<(totW + 255) / 256, 256, 0, stream>>>(bw2, sw2, sc2, W2, totW);

    const size_t NEED_A = (8ull << 20) + ((size_t)TOKENS * D_IN * 8 * 2)      // F1 32MB
                        + ((size_t)TOKENS * D_HID * 8 * 2);                   // F2 128MB

    if (ws_size >= NEED_A) {
        __hip_bfloat16* F1 = (__hip_bfloat16*)(ws + (8ull << 20));
        __hip_bfloat16* F2 = (__hip_bfloat16*)(ws + (8ull << 20) + (32ull << 20));

        hipMemsetAsync(d_out, 0, (size_t)out_size * sizeof(float), stream);

        const int totX = TOKENS * D_IN;   // 2M
        expand_x<<<(totX + 255) / 256, 256, 0, stream>>>(x, F1, totX);

        // GEMM1: (8192 x 2048) @ (1024 x 2048)^T, GELU+expand -> F2
        kan_gemm_f<128, 128, 1>
            <<<dim3(TOKENS / 128, D_HID / 128, 1), 256, 0, stream>>>(
                F1, W1, nullptr, F2, D_IN * 8, D_HID);

        // GEMM2: (8192 x 8192) @ (256 x 8192)^T, split-K=2, atomic into out
        kan_gemm_f<64, 128, 2>
            <<<dim3(TOKENS / 64, D_IN / 128, 2), 256, 0, stream>>>(
                F2, W2, out, nullptr, D_HID * 8, D_IN);
    } else {
        // Tier C: round-1 fused path (40MB ws)
        float* hbuf = (float*)(ws + (8ull << 20));   // 32MB
        kan_gemm_fused<128, 128, 2, 2, true>
            <<<dim3(TOKENS / 128, D_HID / 128), 256, 0, stream>>>(x, W1, hbuf, D_IN, D_HID);
        kan_gemm_fused<64, 128, 2, 2, false>
            <<<dim3(TOKENS / 64, D_IN / 128), 256, 0, stream>>>(hbuf, W2, out, D_HID, D_IN);
    }
}

// Round 3
// 191.670 us; speedup vs baseline: 3.5632x; 1.0690x over previous
//
#include <hip/hip_runtime.h>
#include <hip/hip_bf16.h>
#include <math.h>

// KAN 2-layer forward, MI355X (gfx950) — round 3.
// Pipeline:
//   prep_weights x2 : fold scaler, pad 7->8, bf16            (W1 4MB, W2 4MB)
//   expand_x        : x -> F1 features (8192 x 256*8) bf16   (32MB)
//   kan_gemm1       : F1 @ W1^T, epilogue exact-GELU -> h f32 (32MB)
//   kan_gemm2       : h-features expanded IN-KERNEL (A-staging), @ W2^T,
//                     BN=256 (full OUT, h read once), split-K=4, atomicAdd.
// No F2 materialization (round-2's 134MB write + 256MB read eliminated).

typedef __attribute__((ext_vector_type(8))) short bf16x8;   // 8 x bf16 (4 VGPRs)
typedef __attribute__((ext_vector_type(4))) float f32x4;

#define TOKENS 8192
#define D_IN   256
#define D_HID  1024

// ---- exact uniform-cubic-B-spline features (closed form, ~55 VALU ops) ----
// knots t_m = (m-3)*(2/3)-1, m=0..9; 6 cubic bases j=0..5; support [t_j, t_j+4h).
// s = (x - t_0)/h; cell c = floor(s); u = s - c. Nonzero bases j = c-3..c with
// standard uniform cubic polynomials. Matches Cox-de Boor recursion exactly.
__device__ __forceinline__ void kan_features(float x, float f[8]) {
    f[0] = x / (1.0f + __expf(-x));          // silu
    const float s = (x + 1.0f) * 1.5f + 3.0f;
    const float cf = floorf(s);
    const float u = s - cf;
    const int c = (int)cf;
    const float u2 = u * u, u3 = u2 * u;
    const float k6 = 1.0f / 6.0f;
    const float v3 = u3 * k6;                                  // j = c
    const float v2 = (-3.0f * u3 + 3.0f * u2 + 3.0f * u + 1.0f) * k6; // j = c-1
    const float v1 = (3.0f * u3 - 6.0f * u2 + 4.0f) * k6;      // j = c-2
    const float w1 = 1.0f - u;
    const float v0 = w1 * w1 * w1 * k6;                        // j = c-3
    const bool in = (s >= 0.0f) && (s < 9.0f);
#pragma unroll
    for (int j = 0; j < 6; ++j) {
        int d = c - j;
        float bv = (d == 0) ? v3 : (d == 1) ? v2 : (d == 2) ? v1 : (d == 3) ? v0 : 0.0f;
        f[1 + j] = in ? bv : 0.0f;
    }
    f[7] = 0.0f;
}

__device__ __forceinline__ void features_to_bf16(const float f[8], __hip_bfloat16 fb[8]) {
#pragma unroll
    for (int j = 0; j < 8; ++j) fb[j] = __float2bfloat16(f[j]);
}

// ---------------- weight prep: fold scaler, pad 7->8, cast bf16 ----------------
__global__ void prep_weights(const float* __restrict__ bw,
                             const float* __restrict__ sw,
                             const float* __restrict__ sc,
                             __hip_bfloat16* __restrict__ Waug, int total) {
    int idx = blockIdx.x * blockDim.x + threadIdx.x;
    if (idx >= total) return;
    float scl = sc[idx];
    __hip_bfloat16 row[8];
    row[0] = __float2bfloat16(bw[idx]);
#pragma unroll
    for (int j = 0; j < 6; ++j)
        row[1 + j] = __float2bfloat16(sw[idx * 6 + j] * scl);
    row[7] = __float2bfloat16(0.0f);
    *(bf16x8*)&Waug[(size_t)idx * 8] = *(bf16x8*)row;
}

// ---------------- x -> F1 features, once ----------------
__global__ void expand_x(const float* __restrict__ X, __hip_bfloat16* __restrict__ F,
                         int total) {
    int idx = blockIdx.x * blockDim.x + threadIdx.x;
    if (idx >= total) return;
    float f[8];
    kan_features(X[idx], f);
    __hip_bfloat16 fb[8];
    features_to_bf16(f, fb);
    *(bf16x8*)&F[(size_t)idx * 8] = *(bf16x8*)fb;
}

// ---------------- GEMM1 (m97 structure): H = GELU(F1 @ W1^T) ----------------
template<int BM, int BN>
__global__ __launch_bounds__(256)
void kan_gemm1(const __hip_bfloat16* __restrict__ A,
               const __hip_bfloat16* __restrict__ W,
               float* __restrict__ H) {
    constexpr int K = D_IN * 8;                 // 2048
    constexpr int WTM = BM / 2, WTN = BN / 2;
    constexpr int FM = WTM / 16, FN = WTN / 16;
    __shared__ __hip_bfloat16 Al[BM * 32];
    __shared__ __hip_bfloat16 Bl[BN * 32];

    const int tid = threadIdx.x;
    const int wid = tid >> 6, lane = tid & 63;
    const int wm = wid >> 1, wn = wid & 1;
    const int lr = lane & 15, lg = lane >> 4;
    const int n0 = blockIdx.x * BM, o0 = blockIdx.y * BN;

    f32x4 acc[FM][FN] = {};

    for (int kc = 0; kc < K / 32; ++kc) {
#pragma unroll
        for (int p = 0; p < BM * 64 / 4096; ++p) {
            int item = tid + p * 256;
            const __hip_bfloat16* src =
                A + (size_t)(n0 + (item >> 2)) * K + kc * 32 + (item & 3) * 8;
            __builtin_amdgcn_global_load_lds(
                (const __attribute__((address_space(1))) void*)src,
                (__attribute__((address_space(3))) void*)&Al[item * 8], 16, 0, 0);
        }
#pragma unroll
        for (int p = 0; p < BN * 64 / 4096; ++p) {
            int item = tid + p * 256;
            const __hip_bfloat16* src =
                W + (size_t)(o0 + (item >> 2)) * K + kc * 32 + (item & 3) * 8;
            __builtin_amdgcn_global_load_lds(
                (const __attribute__((address_space(1))) void*)src,
                (__attribute__((address_space(3))) void*)&Bl[item * 8], 16, 0, 0);
        }
        __syncthreads();
        bf16x8 af[FM], bfr[FN];
#pragma unroll
        for (int fm = 0; fm < FM; ++fm)
            af[fm] = *(const bf16x8*)&Al[(wm * WTM + fm * 16 + lr) * 32 + lg * 8];
#pragma unroll
        for (int fn = 0; fn < FN; ++fn)
            bfr[fn] = *(const bf16x8*)&Bl[(wn * WTN + fn * 16 + lr) * 32 + lg * 8];
#pragma unroll
        for (int fm = 0; fm < FM; ++fm)
#pragma unroll
            for (int fn = 0; fn < FN; ++fn)
                acc[fm][fn] = __builtin_amdgcn_mfma_f32_16x16x32_bf16(
                    af[fm], bfr[fn], acc[fm][fn], 0, 0, 0);
        __syncthreads();
    }
    // epilogue: exact GELU, f32 store
#pragma unroll
    for (int fm = 0; fm < FM; ++fm) {
#pragma unroll
        for (int fn = 0; fn < FN; ++fn) {
            int col = o0 + wn * WTN + fn * 16 + lr;
#pragma unroll
            for (int r = 0; r < 4; ++r) {
                int row = n0 + wm * WTM + fm * 16 + lg * 4 + r;
                float v = acc[fm][fn][r];
                float g = 0.5f * v * (1.0f + erff(v * 0.70710678118f));
                H[(size_t)row * D_HID + col] = g;
            }
        }
    }
}

// ---------------- GEMM2: out += expand(h) @ W2^T, fused A-expansion ----------------
// BM=64, BN=OUT=256, 4 waves 1x4 (WTM=64, WTN=64), split-K over blockIdx.z.
__global__ __launch_bounds__(256)
void kan_gemm2(const float* __restrict__ H,
               const __hip_bfloat16* __restrict__ W,
               float* __restrict__ Y) {
    constexpr int BM = 64, BN = 256, OUT = D_IN, KD = D_HID * 8;  // 8192
    constexpr int FM = 4, FN = 4;
    __shared__ __hip_bfloat16 Al[BM * 32];
    __shared__ __hip_bfloat16 Bl[BN * 32];

    const int tid = threadIdx.x;
    const int wid = tid >> 6, lane = tid & 63;
    const int lr = lane & 15, lg = lane >> 4;
    const int n0 = blockIdx.x * BM;

    const int nsteps = KD / 32;                  // 256 (4 h-cols per step)
    const int per = nsteps / gridDim.z;
    const int ks0 = blockIdx.z * per, ks1 = ks0 + per;

    f32x4 acc[FM][FN] = {};

    // each thread owns one (row, h-col-within-chunk) staging item
    const int arow = tid >> 2, aio = tid & 3;
    const float* hp = H + (size_t)(n0 + arow) * D_HID + aio;
    float hv = hp[ks0 * 4];                      // prologue load

    for (int kc = ks0; kc < ks1; ++kc) {
        float hcur = hv;
        if (kc + 1 < ks1) hv = hp[(kc + 1) * 4]; // prefetch next (hidden under MFMA)
        float f[8];
        kan_features(hcur, f);
        __hip_bfloat16 fb[8];
        features_to_bf16(f, fb);
        *(bf16x8*)&Al[tid * 8] = *(bf16x8*)fb;   // linear: row*32 + aio*8
        // B tile: all 256 out-rows x 32 k
#pragma unroll
        for (int p = 0; p < 4; ++p) {
            int item = tid + p * 256;
            const __hip_bfloat16* src =
                W + (size_t)(item >> 2) * KD + kc * 32 + (item & 3) * 8;
            __builtin_amdgcn_global_load_lds(
                (const __attribute__((address_space(1))) void*)src,
                (__attribute__((address_space(3))) void*)&Bl[item * 8], 16, 0, 0);
        }
        __syncthreads();
        bf16x8 af[FM], bfr[FN];
#pragma unroll
        for (int fm = 0; fm < FM; ++fm)
            af[fm] = *(const bf16x8*)&Al[(fm * 16 + lr) * 32 + lg * 8];
#pragma unroll
        for (int fn = 0; fn < FN; ++fn)
            bfr[fn] = *(const bf16x8*)&Bl[(wid * 64 + fn * 16 + lr) * 32 + lg * 8];
#pragma unroll
        for (int fm = 0; fm < FM; ++fm)
#pragma unroll
            for (int fn = 0; fn < FN; ++fn)
                acc[fm][fn] = __builtin_amdgcn_mfma_f32_16x16x32_bf16(
                    af[fm], bfr[fn], acc[fm][fn], 0, 0, 0);
        __syncthreads();
    }
    // epilogue: split-K accumulate
#pragma unroll
    for (int fm = 0; fm < FM; ++fm) {
#pragma unroll
        for (int fn = 0; fn < FN; ++fn) {
            int col = wid * 64 + fn * 16 + lr;
#pragma unroll
            for (int r = 0; r < 4; ++r) {
                int row = n0 + fm * 16 + lg * 4 + r;
                atomicAdd(&Y[(size_t)row * OUT + col], acc[fm][fn][r]);
            }
        }
    }
}

extern "C" void kernel_launch(void* const* d_in, const int* in_sizes, int n_in,
                              void* d_out, int out_size, void* d_ws, size_t ws_size,
                              hipStream_t stream) {
    const float* x   = (const float*)d_in[0];
    const float* bw1 = (const float*)d_in[1];
    const float* sw1 = (const float*)d_in[2];
    const float* sc1 = (const float*)d_in[3];
    const float* bw2 = (const float*)d_in[4];
    const float* sw2 = (const float*)d_in[5];
    const float* sc2 = (const float*)d_in[6];
    float* out = (float*)d_out;

    char* ws = (char*)d_ws;
    __hip_bfloat16* W1 = (__hip_bfloat16*)ws;                   // 4MB
    __hip_bfloat16* W2 = (__hip_bfloat16*)(ws + (4ull << 20));  // 4MB
    __hip_bfloat16* F1 = (__hip_bfloat16*)(ws + (8ull << 20));  // 32MB
    float*          Hb = (float*)(ws + (40ull << 20));          // 32MB

    if (ws_size < (72ull << 20)) return;   // validation will catch

    const int totW = D_HID * D_IN;   // 262144
    prep_weights<<<(totW + 255) / 256, 256, 0, stream>>>(bw1, sw1, sc1, W1, totW);
    prep_weights<<<(totW + 255) / 256, 256, 0, stream>>>(bw2, sw2, sc2, W2, totW);

    hipMemsetAsync(d_out, 0, (size_t)out_size * sizeof(float), stream);

    const int totX = TOKENS * D_IN;  // 2M
    expand_x<<<(totX + 255) / 256, 256, 0, stream>>>(x, F1, totX);

    // GEMM1: (8192 x 2048) @ (1024 x 2048)^T + GELU -> Hb
    kan_gemm1<128, 128>
        <<<dim3(TOKENS / 128, D_HID / 128), 256, 0, stream>>>(F1, W1, Hb);

    // GEMM2: expand(Hb) @ (256 x 8192)^T, split-K=4, atomic into out
    kan_gemm2<<<dim3(TOKENS / 64, 1, 4), 256, 0, stream>>>(Hb, W2, out);
}